// Round 20
// baseline (34.132 us; speedup 1.0000x reference)
//
#include <hip/hip_runtime.h>

typedef __attribute__((ext_vector_type(8))) short short8;
typedef __attribute__((ext_vector_type(16))) float f32x16;

#define NROWS 32768        // B*H*W
#define NELEM 262144       // B*C*H*W
#define KCB   8192
#define ROWS_PB 32         // rows per block (one 32-row MFMA tile)
#define NWAVE 8            // k-waves per block; each scans KCB/8 = 1024 entries

// round-to-nearest-even fp32 -> bf16 (finite values only)
static __device__ __forceinline__ short to_bf16(float x) {
    unsigned u = __float_as_uint(x);
    unsigned r = (u + 0x7FFFu + ((u >> 16) & 1u)) >> 16;
    return (short)r;
}

// Prep (R8/R10-verified layout): codebook group g (32 entries) = 1KB:
// bytes [0,512) = entries' ch0..7 (16B each, k=0..7),
// bytes [512,1024) = entries' [-0.5*||e||^2, 0 x7] (k=8..15).
// Also pack z rows (8 bf16) and zero the loss slot.
__global__ __launch_bounds__(256) void vq_prep(
    const float* __restrict__ z, const float* __restrict__ cb,
    short8* __restrict__ cbb32, short8* __restrict__ pka, float* __restrict__ out)
{
    int gid = blockIdx.x * 256 + threadIdx.x;
    if (gid == 0) out[NELEM] = 0.0f;
    if (gid < KCB) {
        const float4* p = (const float4*)(cb + (size_t)gid * 8);
        float4 a = p[0], b = p[1];
        float h = -0.5f * (a.x*a.x + a.y*a.y + a.z*a.z + a.w*a.w
                         + b.x*b.x + b.y*b.y + b.z*b.z + b.w*b.w);
        short8 lo = { to_bf16(a.x), to_bf16(a.y), to_bf16(a.z), to_bf16(a.w),
                      to_bf16(b.x), to_bf16(b.y), to_bf16(b.z), to_bf16(b.w) };
        short8 hi = { to_bf16(h), 0, 0, 0, 0, 0, 0, 0 };
        cbb32[(gid >> 5) * 64 + (gid & 31)]      = lo;
        cbb32[(gid >> 5) * 64 + 32 + (gid & 31)] = hi;
    } else {
        int n = gid - KCB;
        int bb = n >> 12, hw = n & 4095;
        const float* zp = z + (size_t)bb * 32768 + hw;
        short8 v = { to_bf16(zp[0]),     to_bf16(zp[4096]),
                     to_bf16(zp[8192]),  to_bf16(zp[12288]),
                     to_bf16(zp[16384]), to_bf16(zp[20480]),
                     to_bf16(zp[24576]), to_bf16(zp[28672]) };
        pka[n] = v;
    }
}

#define SGB(mask, n) __builtin_amdgcn_sched_group_barrier((mask), (n), 0)
// LLVM SchedGroupMask: VALU=0x2, MFMA=0x8, VMEM_READ=0x20

// Scan: R19 chassis (best measured, 33.5us) + T19 sched_group_barrier pinning.
// Pack is PURE HIP (v_and_or_b32 + v_max3_f32 emitted by compiler -> the
// scheduler can classify them; inline asm could not be grouped). Per
// steady-state iteration the pinned emission order is:
//   {2 MFMA (dB) ; 2 VMEM loads (bB) ; 48 VALU pack(dA) ;
//    2 MFMA (dA) ; 2 VMEM loads (bA) ; 48 VALU pack(dB)}
// guaranteeing the 2-slot pipeline survives into the .s (the inline-asm
// version gave the compiler license to re-serialize it -- untestable till now).
__global__ __launch_bounds__(512, 4) void vq_scan32(
    const float* __restrict__ z, const float* __restrict__ cb,
    const short8* __restrict__ cbb32, const short8* __restrict__ pka,
    float* __restrict__ out)
{
    __shared__ float sbest[NWAVE][ROWS_PB];
    __shared__ float lsum[NWAVE];

    const int tid  = threadIdx.x;
    const int lane = tid & 63;
    const int w    = tid >> 6;            // k-wave 0..7
    const int c32  = lane & 31;
    const int hi   = lane >> 5;

    const int row0 = blockIdx.x * ROWS_PB;

    // A frag: lanes 0..31 = row channels (k=0..7); lanes 32..63 = [1.0,0...] (k=8)
    short8 af;
    if (hi == 0) {
        af = pka[row0 + c32];
    } else {
        short8 one = {(short)0x3F80, 0, 0, 0, 0, 0, 0, 0};
        af = one;
    }

    const int kbase = w * (KCB / NWAVE);  // 1024 entries = 16 pairs of groups
    const char* bpc = (const char*)cbb32 + (size_t)kbase * 32
                    + (size_t)c32 * 16 + (size_t)hi * 512;

    float best[16];
    #pragma unroll
    for (int r = 0; r < 16; ++r)
        best[r] = __uint_as_float(0xFF800000u);   // -inf

    const f32x16 z16 = {0.f,0.f,0.f,0.f,0.f,0.f,0.f,0.f,
                        0.f,0.f,0.f,0.f,0.f,0.f,0.f,0.f};

#define LDP0(P) (*(const short8*)(bpc + (size_t)(P) * 2048))
#define LDP1(P) (*(const short8*)(bpc + (size_t)(P) * 2048 + 1024))
#define PACK16(D0, D1, IV)                                                     \
    {   const unsigned iv0_ = (IV), iv1_ = (IV) - 32u;                         \
        _Pragma("unroll")                                                      \
        for (int r = 0; r < 16; ++r) {                                         \
            float p0 = __uint_as_float(                                        \
                (__float_as_uint((D0)[r]) & 0xFFFFE000u) | iv0_);              \
            float p1 = __uint_as_float(                                        \
                (__float_as_uint((D1)[r]) & 0xFFFFE000u) | iv1_);              \
            best[r] = fmaxf(fmaxf(p0, p1), best[r]);  /* v_max3_f32 */         \
        }                                                                      }

    unsigned ivA = 8191u - (unsigned)kbase - (unsigned)c32;  // pair 0 base
    unsigned ivB = ivA - 64u;                                // pair 1 base

    // ---- prologue ----
    short8 bA0 = LDP0(0), bA1 = LDP1(0);
    short8 bB0 = LDP0(1), bB1 = LDP1(1);
    f32x16 dA0 = __builtin_amdgcn_mfma_f32_32x32x16_bf16(af, bA0, z16, 0, 0, 0);
    f32x16 dA1 = __builtin_amdgcn_mfma_f32_32x32x16_bf16(af, bA1, z16, 0, 0, 0);
    bA0 = LDP0(2); bA1 = LDP1(2);

    // ---- steady state: i handles pack(2i) and pack(2i+1) ----
    #pragma unroll 1
    for (int i = 0; i < 7; ++i) {
        f32x16 dB0 = __builtin_amdgcn_mfma_f32_32x32x16_bf16(af, bB0, z16, 0, 0, 0);
        f32x16 dB1 = __builtin_amdgcn_mfma_f32_32x32x16_bf16(af, bB1, z16, 0, 0, 0);
        bB0 = LDP0(2 * i + 3); bB1 = LDP1(2 * i + 3);
        PACK16(dA0, dA1, ivA);                 // covers dB latency
        ivA -= 128u;
        dA0 = __builtin_amdgcn_mfma_f32_32x32x16_bf16(af, bA0, z16, 0, 0, 0);
        dA1 = __builtin_amdgcn_mfma_f32_32x32x16_bf16(af, bA1, z16, 0, 0, 0);
        {   const int pn = (2 * i + 4) & 15;   // i=6 wraps -> dead load, harmless
            bA0 = LDP0(pn); bA1 = LDP1(pn); }
        PACK16(dB0, dB1, ivB);                 // covers dA latency
        ivB -= 128u;

        // T19: pin this iteration's schedule (compile-time interleave)
        SGB(0x8, 2);    // 2 MFMA  (dB0,dB1)
        SGB(0x20, 2);   // 2 VMEM_READ (bB refill)
        SGB(0x2, 48);   // 48 VALU (pack dA)
        SGB(0x8, 2);    // 2 MFMA  (dA0,dA1)
        SGB(0x20, 2);   // 2 VMEM_READ (bA refill)
        SGB(0x2, 48);   // 48 VALU (pack dB)
    }

    // ---- epilogue: pairs 14 (in dA) and 15 (bB) ----
    {
        f32x16 dB0 = __builtin_amdgcn_mfma_f32_32x32x16_bf16(af, bB0, z16, 0, 0, 0);
        f32x16 dB1 = __builtin_amdgcn_mfma_f32_32x32x16_bf16(af, bB1, z16, 0, 0, 0);
        PACK16(dA0, dA1, ivA);
        PACK16(dB0, dB1, ivB);
    }

    // ---- reduce over 32 entry-cols ----
    #pragma unroll
    for (int d = 1; d < 32; d <<= 1)
        #pragma unroll
        for (int r = 0; r < 16; ++r)
            best[r] = fmaxf(best[r], __shfl_xor(best[r], d));

    if (c32 == 0) {
        #pragma unroll
        for (int r = 0; r < 16; ++r) {
            const int m = (r & 3) + ((r >> 2) << 3) + (hi << 2);  // C/D row map (verified)
            sbest[w][m] = best[r];
        }
    }
    __syncthreads();

    // ---- emit: 32 rows x 8 ch, one elem/thread (first 256 threads) ----
    float sq = 0.0f;
    if (tid < 256) {
        const int pos = tid & 31;
        const int ch  = tid >> 5;
        float m = sbest[0][pos];
        #pragma unroll
        for (int kw = 1; kw < NWAVE; ++kw) m = fmaxf(m, sbest[kw][pos]);
        const int k = 8191 - (int)(__float_as_uint(m) & 8191u);

        const int n = row0 + pos;
        const size_t o = ((size_t)(n >> 12)) * 32768 + (size_t)ch * 4096
                       + (size_t)(n & 4095);
        float ev = cb[(size_t)k * 8 + ch];
        float zz = z[o];
        out[o] = ev;
        float dd = ev - zz;
        sq = dd * dd;
    }
    #pragma unroll
    for (int off = 32; off > 0; off >>= 1) sq += __shfl_down(sq, off);
    if (lane == 0) lsum[w] = sq;
    __syncthreads();
    if (tid == 0) {
        float s = 0.f;
        #pragma unroll
        for (int kw = 0; kw < NWAVE; ++kw) s += lsum[kw];
        atomicAdd(out + NELEM, s * (1.25f / (float)NELEM));
    }
}

extern "C" void kernel_launch(void* const* d_in, const int* in_sizes, int n_in,
                              void* d_out, int out_size, void* d_ws, size_t ws_size,
                              hipStream_t stream)
{
    const float* z  = (const float*)d_in[0];   // [8, 8, 64, 64] fp32
    const float* cb = (const float*)d_in[1];   // [8192, 8] fp32
    float* out = (float*)d_out;                // 262144 z_q + 1 loss
    short8* cbb32 = (short8*)d_ws;                       // 256 KB packed codebook
    short8* pka   = (short8*)((char*)d_ws + 256 * 1024); // 512 KB packed z rows

    vq_prep<<<(KCB + NROWS) / 256, 256, 0, stream>>>(z, cb, cbb32, pka, out);
    vq_scan32<<<NROWS / ROWS_PB, 512, 0, stream>>>(z, cb, cbb32, pka, out);
}

// Round 21
// 33.708 us; speedup vs baseline: 1.0126x; 1.0126x over previous
//
#include <hip/hip_runtime.h>

typedef __attribute__((ext_vector_type(8))) short short8;
typedef __attribute__((ext_vector_type(16))) float f32x16;

#define NROWS 32768        // B*H*W
#define NELEM 262144       // B*C*H*W
#define KCB   8192
#define ROWS_PB 32         // rows per block (one 32-row MFMA tile)
#define NWAVE 8            // k-waves per block; each scans KCB/8 = 1024 entries

// round-to-nearest-even fp32 -> bf16 (finite values only)
static __device__ __forceinline__ short to_bf16(float x) {
    unsigned u = __float_as_uint(x);
    unsigned r = (u + 0x7FFFu + ((u >> 16) & 1u)) >> 16;
    return (short)r;
}

// Prep (R8/R10-verified layout): codebook group g (32 entries) = 1KB:
// bytes [0,512) = entries' ch0..7 (16B each, k=0..7),
// bytes [512,1024) = entries' [-0.5*||e||^2, 0 x7] (k=8..15).
// Also pack z rows (8 bf16) and zero the loss slot.
__global__ __launch_bounds__(256) void vq_prep(
    const float* __restrict__ z, const float* __restrict__ cb,
    short8* __restrict__ cbb32, short8* __restrict__ pka, float* __restrict__ out)
{
    int gid = blockIdx.x * 256 + threadIdx.x;
    if (gid == 0) out[NELEM] = 0.0f;
    if (gid < KCB) {
        const float4* p = (const float4*)(cb + (size_t)gid * 8);
        float4 a = p[0], b = p[1];
        float h = -0.5f * (a.x*a.x + a.y*a.y + a.z*a.z + a.w*a.w
                         + b.x*b.x + b.y*b.y + b.z*b.z + b.w*b.w);
        short8 lo = { to_bf16(a.x), to_bf16(a.y), to_bf16(a.z), to_bf16(a.w),
                      to_bf16(b.x), to_bf16(b.y), to_bf16(b.z), to_bf16(b.w) };
        short8 hi = { to_bf16(h), 0, 0, 0, 0, 0, 0, 0 };
        cbb32[(gid >> 5) * 64 + (gid & 31)]      = lo;
        cbb32[(gid >> 5) * 64 + 32 + (gid & 31)] = hi;
    } else {
        int n = gid - KCB;
        int bb = n >> 12, hw = n & 4095;
        const float* zp = z + (size_t)bb * 32768 + hw;
        short8 v = { to_bf16(zp[0]),     to_bf16(zp[4096]),
                     to_bf16(zp[8192]),  to_bf16(zp[12288]),
                     to_bf16(zp[16384]), to_bf16(zp[20480]),
                     to_bf16(zp[24576]), to_bf16(zp[28672]) };
        pka[n] = v;
    }
}

// 3-inst pack+merge: best = max3((s0&M)|iv0, (s1&M)|iv1, best)
static __device__ __forceinline__ void packmax3(float& best, float s0, float s1,
                                                unsigned iv0, unsigned iv1)
{
    float p0, p1;
    asm("v_and_or_b32 %0, %1, %2, %3"
        : "=v"(p0) : "v"(s0), "s"(0xFFFFE000u), "v"(iv0));
    asm("v_and_or_b32 %0, %1, %2, %3"
        : "=v"(p1) : "v"(s1), "s"(0xFFFFE000u), "v"(iv1));
    asm("v_max3_f32 %0, %1, %2, %0"
        : "+v"(best) : "v"(p0), "v"(p1));
}

// Scan: 1024 blocks x 512 thr (8 k-waves), 32 rows/block, 32x32x16 MFMA.
// Explicit 2-slot in-wave pipeline: pair p+1's MFMAs issue BEFORE packing
// pair p (pack's ~100 VALU cyc hides MFMA result latency); buffers refilled
// right after consumption. Named regs + unroll 1 -> no spill.
// Plateau note (20 rounds): scan is latency-bound at ~35% MfmaUtil; null
// levers = TLP, ILP depth, LDS/global staging, MFMA shape, VALU/score,
// warm-prefetch, setprio, sched_group_barrier. Best measured: 33.5us.
__global__ __launch_bounds__(512, 4) void vq_scan32(
    const float* __restrict__ z, const float* __restrict__ cb,
    const short8* __restrict__ cbb32, const short8* __restrict__ pka,
    float* __restrict__ out)
{
    __shared__ float sbest[NWAVE][ROWS_PB];
    __shared__ float lsum[NWAVE];

    const int tid  = threadIdx.x;
    const int lane = tid & 63;
    const int w    = tid >> 6;            // k-wave 0..7
    const int c32  = lane & 31;
    const int hi   = lane >> 5;

    const int row0 = blockIdx.x * ROWS_PB;

    // A frag: lanes 0..31 = row channels (k=0..7); lanes 32..63 = [1.0,0...] (k=8)
    short8 af;
    if (hi == 0) {
        af = pka[row0 + c32];
    } else {
        short8 one = {(short)0x3F80, 0, 0, 0, 0, 0, 0, 0};
        af = one;
    }

    const int kbase = w * (KCB / NWAVE);  // 1024 entries = 16 pairs of groups
    const char* bpc = (const char*)cbb32 + (size_t)kbase * 32
                    + (size_t)c32 * 16 + (size_t)hi * 512;

    float best[16];
    #pragma unroll
    for (int r = 0; r < 16; ++r)
        best[r] = __uint_as_float(0xFF800000u);   // -inf

    const f32x16 z16 = {0.f,0.f,0.f,0.f,0.f,0.f,0.f,0.f,
                        0.f,0.f,0.f,0.f,0.f,0.f,0.f,0.f};

#define LDP0(P) (*(const short8*)(bpc + (size_t)(P) * 2048))
#define LDP1(P) (*(const short8*)(bpc + (size_t)(P) * 2048 + 1024))
#define PACK16(D0, D1, IV)                                            \
    {   const unsigned iv0_ = (IV), iv1_ = (IV) - 32u;                \
        _Pragma("unroll")                                             \
        for (int r = 0; r < 16; ++r)                                  \
            packmax3(best[r], (D0)[r], (D1)[r], iv0_, iv1_);          }

    unsigned ivA = 8191u - (unsigned)kbase - (unsigned)c32;  // pair 0 base
    unsigned ivB = ivA - 64u;                                // pair 1 base

    // ---- prologue ----
    short8 bA0 = LDP0(0), bA1 = LDP1(0);
    short8 bB0 = LDP0(1), bB1 = LDP1(1);
    f32x16 dA0 = __builtin_amdgcn_mfma_f32_32x32x16_bf16(af, bA0, z16, 0, 0, 0);
    f32x16 dA1 = __builtin_amdgcn_mfma_f32_32x32x16_bf16(af, bA1, z16, 0, 0, 0);
    bA0 = LDP0(2); bA1 = LDP1(2);

    // ---- steady state: i handles pack(2i) and pack(2i+1) ----
    #pragma unroll 1
    for (int i = 0; i < 7; ++i) {
        f32x16 dB0 = __builtin_amdgcn_mfma_f32_32x32x16_bf16(af, bB0, z16, 0, 0, 0);
        f32x16 dB1 = __builtin_amdgcn_mfma_f32_32x32x16_bf16(af, bB1, z16, 0, 0, 0);
        bB0 = LDP0(2 * i + 3); bB1 = LDP1(2 * i + 3);
        PACK16(dA0, dA1, ivA);                 // covers dB latency
        ivA -= 128u;
        dA0 = __builtin_amdgcn_mfma_f32_32x32x16_bf16(af, bA0, z16, 0, 0, 0);
        dA1 = __builtin_amdgcn_mfma_f32_32x32x16_bf16(af, bA1, z16, 0, 0, 0);
        {   const int pn = (2 * i + 4) & 15;   // i=6 wraps -> dead load, harmless
            bA0 = LDP0(pn); bA1 = LDP1(pn); }
        PACK16(dB0, dB1, ivB);                 // covers dA latency
        ivB -= 128u;
    }

    // ---- epilogue: pairs 14 (in dA) and 15 (bB) ----
    {
        f32x16 dB0 = __builtin_amdgcn_mfma_f32_32x32x16_bf16(af, bB0, z16, 0, 0, 0);
        f32x16 dB1 = __builtin_amdgcn_mfma_f32_32x32x16_bf16(af, bB1, z16, 0, 0, 0);
        PACK16(dA0, dA1, ivA);
        PACK16(dB0, dB1, ivB);
    }

    // ---- reduce over 32 entry-cols ----
    #pragma unroll
    for (int d = 1; d < 32; d <<= 1)
        #pragma unroll
        for (int r = 0; r < 16; ++r)
            best[r] = fmaxf(best[r], __shfl_xor(best[r], d));

    if (c32 == 0) {
        #pragma unroll
        for (int r = 0; r < 16; ++r) {
            const int m = (r & 3) + ((r >> 2) << 3) + (hi << 2);  // C/D row map (verified)
            sbest[w][m] = best[r];
        }
    }
    __syncthreads();

    // ---- emit: 32 rows x 8 ch, one elem/thread (first 256 threads) ----
    float sq = 0.0f;
    if (tid < 256) {
        const int pos = tid & 31;
        const int ch  = tid >> 5;
        float m = sbest[0][pos];
        #pragma unroll
        for (int kw = 1; kw < NWAVE; ++kw) m = fmaxf(m, sbest[kw][pos]);
        const int k = 8191 - (int)(__float_as_uint(m) & 8191u);

        const int n = row0 + pos;
        const size_t o = ((size_t)(n >> 12)) * 32768 + (size_t)ch * 4096
                       + (size_t)(n & 4095);
        float ev = cb[(size_t)k * 8 + ch];
        float zz = z[o];
        out[o] = ev;
        float dd = ev - zz;
        sq = dd * dd;
    }
    #pragma unroll
    for (int off = 32; off > 0; off >>= 1) sq += __shfl_down(sq, off);
    if (lane == 0) lsum[w] = sq;
    __syncthreads();
    if (tid == 0) {
        float s = 0.f;
        #pragma unroll
        for (int kw = 0; kw < NWAVE; ++kw) s += lsum[kw];
        atomicAdd(out + NELEM, s * (1.25f / (float)NELEM));
    }
}

extern "C" void kernel_launch(void* const* d_in, const int* in_sizes, int n_in,
                              void* d_out, int out_size, void* d_ws, size_t ws_size,
                              hipStream_t stream)
{
    const float* z  = (const float*)d_in[0];   // [8, 8, 64, 64] fp32
    const float* cb = (const float*)d_in[1];   // [8192, 8] fp32
    float* out = (float*)d_out;                // 262144 z_q + 1 loss
    short8* cbb32 = (short8*)d_ws;                       // 256 KB packed codebook
    short8* pka   = (short8*)((char*)d_ws + 256 * 1024); // 512 KB packed z rows

    vq_prep<<<(KCB + NROWS) / 256, 256, 0, stream>>>(z, cb, cbb32, pka, out);
    vq_scan32<<<NROWS / ROWS_PB, 512, 0, stream>>>(z, cb, cbb32, pka, out);
}